// Round 8
// baseline (27.008 us; speedup 1.0000x reference)
//
#include <hip/hip_runtime.h>
#include <math.h>

#define NENT 33          // tap entries 0..32
#define NPAIR 32         // pair e = (t[e], t[e+1]), e = 0..31
#define PPT 4
#define NBLK 2048

__global__ __launch_bounds__(256) void yuksel_fused(
    const float* __restrict__ x, const float* __restrict__ P,
    float* __restrict__ out, int N)
{
    // 5 tap arrays stored as overlapping pairs: ltab2[k][e] = (t[e], t[e+1])
    __shared__ float ltab2[5][NPAIR][2];
    const int tid = threadIdx.x;

    // ---- fully parallel table build: 33 independent entries ----
    // ptilde[e] = p[e] except ptilde[1] = (p[0]+p[2])/4 + p[1]/2
    // stilde[e] = sig[e] except stilde[1] = (sig[0]+sig[2])/16 + sig[1]/4
    if (tid < NENT) {
        const int e = tid;
        float vals[5];
        if (e == 1) {
            float r0[5], r1[5], r2[5];
            for (int r = 0; r < 3; ++r) {
                float* dst = r==0 ? r0 : (r==1 ? r1 : r2);
                float a = P[r*5+2], b = P[r*5+3], c = P[r*5+4];
                dst[0] = P[r*5+0]; dst[1] = P[r*5+1];
                dst[2] = a*a + b*b; dst[3] = b*(a+c); dst[4] = b*b + c*c;
            }
            for (int k = 0; k < 2; ++k) vals[k] = (r0[k]+r2[k])*0.25f   + r1[k]*0.5f;
            for (int k = 2; k < 5; ++k) vals[k] = (r0[k]+r2[k])*0.0625f + r1[k]*0.25f;
        } else {
            float a = P[e*5+2], b = P[e*5+3], c = P[e*5+4];
            vals[0] = P[e*5+0]; vals[1] = P[e*5+1];
            vals[2] = a*a + b*b; vals[3] = b*(a+c); vals[4] = b*b + c*c;
        }
#pragma unroll
        for (int k = 0; k < 5; ++k) {
            if (e < NPAIR) ltab2[k][e][0]   = vals[k];   // as low half of pair e
            if (e >= 1)    ltab2[k][e-1][1] = vals[k];   // as high half of pair e-1
        }
    }
    __syncthreads();

    // ---- grid-stride eval: 4-tap filter per point, 10x ds_read_b64 ----
    const long long stride = (long long)gridDim.x * 256 * PPT;
    for (long long j0 = ((long long)blockIdx.x * 256 + tid) * PPT; j0 < N; j0 += stride) {
        float4 xv = *reinterpret_cast<const float4*>(x + j0);
        float xs[PPT] = { xv.x, xv.y, xv.z, xv.w };
        float mu[2*PPT], sg[3*PPT];

#pragma unroll
        for (int q = 0; q < PPT; ++q) {
            float u  = xs[q] * 30.0f;
            float fi = fminf(fmaxf(floorf(u), 0.0f), 29.0f);
            int   i  = (int)fi;
            float d  = (u - fi) * 0.5f;          // [0, 0.5)
            float e  = d + 0.5f;

            float omd = 1.0f - d, ome = 1.0f - e;
            float bc0 = omd*omd, bc1 = 2.0f*d*omd, bc2 = d*d;
            float bp0 = ome*ome, bp1 = 2.0f*e*ome, bp2 = e*e;

            // cw = cos^2(pi d) = (1 + cos(2 pi d))/2 ; v_cos_f32 arg in revolutions
            float cw  = 0.5f + 0.5f*__builtin_amdgcn_cosf(d);
            float sw  = 1.0f - cw;
            float cw2 = cw*cw, sw2 = sw*sw;

            // mu 4-tap weights
            float w0 = cw*(bp0 - 0.5f*bp1);
            float w1 = 2.0f*cw*bp1 + sw*(bc0 - 0.5f*bc1);
            float w2 = cw*(bp2 - 0.5f*bp1) + 2.0f*sw*bc1;
            float w3 = sw*(bc2 - 0.5f*bc1);
            // sg 4-tap weights (squared basis)
            float a0 = bp0*bp0, a1 = bp1*bp1, a2 = bp2*bp2;
            float c0 = bc0*bc0, c1 = bc1*bc1, c2 = bc2*bc2;
            float v0 = cw2*(a0 - 0.25f*a1);
            float v1 = 4.0f*cw2*a1 + sw2*(c0 - 0.25f*c1);
            float v2 = cw2*(a2 - 0.25f*a1) + 4.0f*sw2*c1;
            float v3 = sw2*(c2 - 0.25f*c1);

            // 10 ds_read_b64: taps {i,i+1} and {i+2,i+3} per array
            const float2* t0 = reinterpret_cast<const float2*>(&ltab2[0][0][0]);
            const float2* t1 = reinterpret_cast<const float2*>(&ltab2[1][0][0]);
            const float2* t2 = reinterpret_cast<const float2*>(&ltab2[2][0][0]);
            const float2* t3 = reinterpret_cast<const float2*>(&ltab2[3][0][0]);
            const float2* t4 = reinterpret_cast<const float2*>(&ltab2[4][0][0]);
            float2 pxA = t0[i], pxB = t0[i+2];
            float2 pyA = t1[i], pyB = t1[i+2];
            float2 s0A = t2[i], s0B = t2[i+2];
            float2 s1A = t3[i], s1B = t3[i+2];
            float2 s2A = t4[i], s2B = t4[i+2];

            mu[2*q+0] = w0*pxA.x + w1*pxA.y + w2*pxB.x + w3*pxB.y;
            mu[2*q+1] = w0*pyA.x + w1*pyA.y + w2*pyB.x + w3*pyB.y;
            sg[3*q+0] = v0*s0A.x + v1*s0A.y + v2*s0B.x + v3*s0B.y;
            sg[3*q+1] = v0*s1A.x + v1*s1A.y + v2*s1B.x + v3*s1B.y;
            sg[3*q+2] = v0*s2A.x + v1*s2A.y + v2*s2B.x + v3*s2B.y;
        }

        float4* muOut = reinterpret_cast<float4*>(out + 2*j0);
        muOut[0] = make_float4(mu[0], mu[1], mu[2], mu[3]);
        muOut[1] = make_float4(mu[4], mu[5], mu[6], mu[7]);
        float4* sgOut = reinterpret_cast<float4*>(out + (size_t)2*N + 3*j0);
        sgOut[0] = make_float4(sg[0], sg[1], sg[2],  sg[3]);
        sgOut[1] = make_float4(sg[4], sg[5], sg[6],  sg[7]);
        sgOut[2] = make_float4(sg[8], sg[9], sg[10], sg[11]);
    }
}

extern "C" void kernel_launch(void* const* d_in, const int* in_sizes, int n_in,
                              void* d_out, int out_size, void* d_ws, size_t ws_size,
                              hipStream_t stream) {
    const float* x = (const float*)d_in[0];
    const float* P = (const float*)d_in[1];
    float* out = (float*)d_out;
    int N = in_sizes[0];

    const int threads = 256;
    const int per_block = threads * PPT;
    long long ntiles = (N + per_block - 1) / per_block;
    int blocks = (int)(ntiles < NBLK ? ntiles : NBLK);
    yuksel_fused<<<blocks, threads, 0, stream>>>(x, P, out, N);
}